// Round 4
// baseline (24194.748 us; speedup 1.0000x reference)
//
#include <hip/hip_runtime.h>
#include <hip/hip_bf16.h>
#include <hip/hip_cooperative_groups.h>
#include <stdint.h>

namespace cg = cooperative_groups;

typedef __attribute__((ext_vector_type(8))) short short8;
typedef __attribute__((ext_vector_type(4))) float floatx4;

#define B_ 64
#define T_ 256
#define H_ 1024
#define LATENT_ 256
#define P_ 128
#define BH_ (B_ * H_)

__device__ __forceinline__ float sigmoidf_(float x) {
    return 1.0f / (1.0f + __expf(-x));
}
__device__ __forceinline__ float tanh_fast(float x) {
    float e = __expf(2.0f * x);
    return 1.0f - 2.0f / (e + 1.0f);
}

// ---------------------------------------------------------------------------
// fp32 -> bf16 conversion, 4 elements/thread. n must be a multiple of 4.
// ---------------------------------------------------------------------------
__global__ __launch_bounds__(256) void cvt_f2b(
    const float* __restrict__ src, __hip_bfloat16* __restrict__ dst, int n)
{
    int i = (blockIdx.x * 256 + threadIdx.x) * 4;
    if (i < n) {
        float4 v = *(const float4*)(src + i);
        dst[i + 0] = __float2bfloat16(v.x);
        dst[i + 1] = __float2bfloat16(v.y);
        dst[i + 2] = __float2bfloat16(v.z);
        dst[i + 3] = __float2bfloat16(v.w);
    }
}

// ---------------------------------------------------------------------------
// h0 = z @ fc_init_w^T + fc_init_b  (64x1024, K=256), fp32 in, bf16 out,
// written into BOTH ring slots used as the t=-1 state (h1 slot 1, h2 slot 3).
// ---------------------------------------------------------------------------
__global__ __launch_bounds__(256) void h0_kernel(
    const float* __restrict__ z,
    const float* __restrict__ fw,
    const float* __restrict__ fb,
    __hip_bfloat16* __restrict__ h1dst,
    __hip_bfloat16* __restrict__ h2dst)
{
    int idx = blockIdx.x * 256 + threadIdx.x;   // 0..65535
    int b = idx >> 10, j = idx & 1023;
    const float* zp = z + b * LATENT_;
    const float* wp = fw + j * LATENT_;
    float acc = fb[j];
    for (int k = 0; k < LATENT_; k += 4) {
        float4 zv = *(const float4*)(zp + k);
        float4 wv = *(const float4*)(wp + k);
        acc += zv.x * wv.x + zv.y * wv.y + zv.z * wv.z + zv.w * wv.w;
    }
    __hip_bfloat16 hb = __float2bfloat16(acc);
    h1dst[idx] = hb;
    h2dst[idx] = hb;
}

// ---------------------------------------------------------------------------
// Generic wave GEMM segment: 4 M-tiles (M=64) x 16 N, nchunks K-chunks of 32.
// A: batch-row base (lane k-offset pre-applied), row stride Astr.
// W: lane's weight row base (nrow*K + koff + ks pre-applied).
// ---------------------------------------------------------------------------
__device__ __forceinline__ void mm_seg(
    const short* __restrict__ A, long Astr,
    const short* __restrict__ W, int nchunks,
    floatx4* acc, int l15)
{
#pragma unroll 2
    for (int c = 0; c < nchunks; ++c) {
        short8 bfrag = *(const short8*)(W + (long)c * 32);
#pragma unroll
        for (int mt = 0; mt < 4; ++mt) {
            short8 afrag = *(const short8*)(A + (long)(mt * 16 + l15) * Astr + (long)c * 32);
            acc[mt] = __builtin_amdgcn_mfma_f32_16x16x32_bf16(afrag, bfrag, acc[mt], 0, 0, 0);
        }
    }
}

struct PParams {
    const __hip_bfloat16 *tseqb, *stokb;
    const __hip_bfloat16 *Wih0b, *Whh0b, *Wih1b, *Whh1b, *owb;
    const float *bih0, *bhh0, *bih1, *bhh1, *ob;
    __hip_bfloat16 *h1ring;   // 2 * B*H
    __hip_bfloat16 *h2ring;   // 4 * B*H
    float* out;               // (B, T, P)
};

// ---------------------------------------------------------------------------
// Persistent pipelined LSTM. 256 blocks x 512 threads, 1 block/CU.
//   blocks   0..127 : layer-1 step t-1   (8 hidden cols x 4 gates each)
//   blocks 128..255 : layer-0 step t     (8 hidden cols x 4 gates each)
//   blocks 128..135 : + out-projection of step t-2 (16 p-cols each)
// One grid.sync per phase; 258 phases. Cell state c lives in registers.
// ---------------------------------------------------------------------------
__global__ __launch_bounds__(512, 2) void lstm_persistent(PParams p)
{
    __shared__ float gbuf[8][64][16];   // 32 KB
    cg::grid_group grid = cg::this_grid();

    const int tid  = threadIdx.x;
    const int bid  = blockIdx.x;
    const int w    = tid >> 6;        // wave 0..7
    const int l    = tid & 63;
    const int l15  = l & 15;
    const int quad = l >> 4;
    const int ks   = quad * 8;        // k-offset (shorts) within a 32-chunk
    const int rh   = w >> 2;          // gate-pair half {0,1}
    const int kh   = w & 3;           // K quarter {0..3}
    const bool isL1 = bid < 128;
    const int colbase = (isL1 ? bid : bid - 128) * 8;
    const int gg   = l15 >> 3;        // which gate of the pair
    const int g    = 2 * rh + gg;     // gate index (i,f,g,o)
    const int nrow = g * H_ + colbase + (l15 & 7);   // weight row

    // Cell assignment: 1 cell per thread (batch cm, col ccl).
    const int cm  = tid >> 3;
    const int ccl = tid & 7;
    const int cj  = colbase + ccl;
    const float* bi = isL1 ? p.bih1 : p.bih0;
    const float* bh = isL1 ? p.bhh1 : p.bhh0;
    const float bsum_i = bi[0 * H_ + cj] + bh[0 * H_ + cj];
    const float bsum_f = bi[1 * H_ + cj] + bh[1 * H_ + cj];
    const float bsum_g = bi[2 * H_ + cj] + bh[2 * H_ + cj];
    const float bsum_o = bi[3 * H_ + cj] + bh[3 * H_ + cj];
    float creg = 0.0f;

    for (int phase = 0; phase < T_ + 2; ++phase) {
        const bool doGemm = isL1 ? (phase >= 1 && phase <= T_) : (phase <= T_ - 1);
        int t = isL1 ? phase - 1 : phase;

        if (doGemm) {
            floatx4 acc[4] = {};
            if (isL1) {
                // gates1 = [h1(t) | h2(t-1)] @ [Wih1 | Whh1]^T, K=2048
                const short* Asel;
                const short* Wsel;
                if (kh < 2) {
                    Asel = (const short*)p.h1ring + (long)(t & 1) * BH_;
                    Wsel = (const short*)p.Wih1b;
                } else {
                    Asel = (const short*)p.h2ring + (long)((t - 1) & 3) * BH_;
                    Wsel = (const short*)p.Whh1b;
                }
                int koff = (kh & 1) * 512;
                mm_seg(Asel + koff + ks, H_,
                       Wsel + (long)nrow * H_ + koff + ks, 16, acc, l15);
            } else {
                // gates0 = [x_t | h1(t-1)] @ [Wih0 | Whh0]^T, K=128+1024
                const short* Ax; long Axs;
                if (t == 0) { Ax = (const short*)p.stokb; Axs = 0; }
                else { Ax = (const short*)p.tseqb + (long)(t - 1) * P_; Axs = (long)T_ * P_; }
                mm_seg(Ax + kh * 32 + ks, Axs,
                       (const short*)p.Wih0b + (long)nrow * P_ + kh * 32 + ks, 1, acc, l15);
                const short* Ah = (const short*)p.h1ring + (long)((t - 1) & 1) * BH_;
                mm_seg(Ah + kh * 256 + ks, H_,
                       (const short*)p.Whh0b + (long)nrow * H_ + kh * 256 + ks, 8, acc, l15);
            }
            // C/D layout: col = lane&15, row = quad*4 + reg
#pragma unroll
            for (int mt = 0; mt < 4; ++mt)
#pragma unroll
                for (int r = 0; r < 4; ++r)
                    gbuf[w][mt * 16 + quad * 4 + r][l15] = acc[mt][r];
        }
        __syncthreads();
        if (doGemm) {
            // LSTM cell for (cm, cj): i,f from waves 0..3; g,o from 4..7.
            float iv = gbuf[0][cm][ccl]     + gbuf[1][cm][ccl]     + gbuf[2][cm][ccl]     + gbuf[3][cm][ccl]     + bsum_i;
            float fv = gbuf[0][cm][8 + ccl] + gbuf[1][cm][8 + ccl] + gbuf[2][cm][8 + ccl] + gbuf[3][cm][8 + ccl] + bsum_f;
            float gv = gbuf[4][cm][ccl]     + gbuf[5][cm][ccl]     + gbuf[6][cm][ccl]     + gbuf[7][cm][ccl]     + bsum_g;
            float ov = gbuf[4][cm][8 + ccl] + gbuf[5][cm][8 + ccl] + gbuf[6][cm][8 + ccl] + gbuf[7][cm][8 + ccl] + bsum_o;
            float cn = sigmoidf_(fv) * creg + sigmoidf_(iv) * tanh_fast(gv);
            float hv = sigmoidf_(ov) * tanh_fast(cn);
            creg = cn;
            __hip_bfloat16* hdst = isL1 ? (p.h2ring + (long)(t & 3) * BH_)
                                        : (p.h1ring + (long)(t & 1) * BH_);
            hdst[cm * H_ + cj] = __float2bfloat16(hv);
        }

        // Out-projection duty: blocks 128..135, step t2 = phase-2.
        if (bid >= 128 && bid < 136 && phase >= 2) {
            int t2 = phase - 2;
            int pbase = (bid - 128) * 16;
            __syncthreads();   // gbuf free (cell reads done)
            floatx4 oacc[4] = {};
            const short* A = (const short*)p.h2ring + (long)(t2 & 3) * BH_ + w * 128 + ks;
            const short* W = (const short*)p.owb + (long)(pbase + l15) * H_ + w * 128 + ks;
            mm_seg(A, H_, W, 4, oacc, l15);
#pragma unroll
            for (int mt = 0; mt < 4; ++mt)
#pragma unroll
                for (int r = 0; r < 4; ++r)
                    gbuf[w][mt * 16 + quad * 4 + r][l15] = oacc[mt][r];
            __syncthreads();
#pragma unroll
            for (int q = 0; q < 2; ++q) {
                int e = tid + q * 512;
                int m = e >> 4, pp = e & 15;
                float v = 0.0f;
#pragma unroll
                for (int w2 = 0; w2 < 8; ++w2) v += gbuf[w2][m][pp];
                v = sigmoidf_(v + p.ob[pbase + pp]);
                p.out[(long)m * (T_ * P_) + (long)t2 * P_ + pbase + pp] = v;
            }
        }

        __threadfence();
        grid.sync();
    }
}

// ---------------------------------------------------------------------------
extern "C" void kernel_launch(void* const* d_in, const int* in_sizes, int n_in,
                              void* d_out, int out_size, void* d_ws, size_t ws_size,
                              hipStream_t stream) {
    const float* z    = (const float*)d_in[0];
    const float* tseq = (const float*)d_in[1];
    const float* fw   = (const float*)d_in[2];
    const float* fb   = (const float*)d_in[3];
    const float* stok = (const float*)d_in[4];
    const float* Wih0 = (const float*)d_in[5];
    const float* Whh0 = (const float*)d_in[6];
    const float* bih0 = (const float*)d_in[7];
    const float* bhh0 = (const float*)d_in[8];
    const float* Wih1 = (const float*)d_in[9];
    const float* Whh1 = (const float*)d_in[10];
    const float* bih1 = (const float*)d_in[11];
    const float* bhh1 = (const float*)d_in[12];
    const float* ow   = (const float*)d_in[13];
    const float* ob   = (const float*)d_in[14];
    float* out = (float*)d_out;

    // Workspace (~30.1 MB): bf16 weight/input copies + h rings.
    char* ws = (char*)d_ws;
    size_t off = 0;
    __hip_bfloat16* Wih0b = (__hip_bfloat16*)(ws + off); off += (size_t)4 * H_ * P_ * 2;
    __hip_bfloat16* Whh0b = (__hip_bfloat16*)(ws + off); off += (size_t)4 * H_ * H_ * 2;
    __hip_bfloat16* Wih1b = (__hip_bfloat16*)(ws + off); off += (size_t)4 * H_ * H_ * 2;
    __hip_bfloat16* Whh1b = (__hip_bfloat16*)(ws + off); off += (size_t)4 * H_ * H_ * 2;
    __hip_bfloat16* owb   = (__hip_bfloat16*)(ws + off); off += (size_t)P_ * H_ * 2;
    __hip_bfloat16* tseqb = (__hip_bfloat16*)(ws + off); off += (size_t)B_ * T_ * P_ * 2;
    __hip_bfloat16* stokb = (__hip_bfloat16*)(ws + off); off += 256;
    __hip_bfloat16* h1ring= (__hip_bfloat16*)(ws + off); off += (size_t)2 * BH_ * 2;
    __hip_bfloat16* h2ring= (__hip_bfloat16*)(ws + off); off += (size_t)4 * BH_ * 2;

    auto cvt = [&](const float* s, __hip_bfloat16* d, int n) {
        hipLaunchKernelGGL(cvt_f2b, dim3((n / 4 + 255) / 256), dim3(256), 0, stream, s, d, n);
    };
    cvt(Wih0, Wih0b, 4 * H_ * P_);
    cvt(Whh0, Whh0b, 4 * H_ * H_);
    cvt(Wih1, Wih1b, 4 * H_ * H_);
    cvt(Whh1, Whh1b, 4 * H_ * H_);
    cvt(ow,   owb,   P_ * H_);
    cvt(tseq, tseqb, B_ * T_ * P_);
    cvt(stok, stokb, P_);

    // h0 into the t=-1 ring slots: h1 slot (-1)&1 = 1, h2 slot (-1)&3 = 3.
    hipLaunchKernelGGL(h0_kernel, dim3(256), dim3(256), 0, stream,
                       z, fw, fb, h1ring + (size_t)1 * BH_, h2ring + (size_t)3 * BH_);

    PParams pp;
    pp.tseqb = tseqb; pp.stokb = stokb;
    pp.Wih0b = Wih0b; pp.Whh0b = Whh0b; pp.Wih1b = Wih1b; pp.Whh1b = Whh1b;
    pp.owb = owb;
    pp.bih0 = bih0; pp.bhh0 = bhh0; pp.bih1 = bih1; pp.bhh1 = bhh1; pp.ob = ob;
    pp.h1ring = h1ring; pp.h2ring = h2ring;
    pp.out = out;
    void* args[] = { &pp };
    hipLaunchCooperativeKernel((void*)lstm_persistent, dim3(256), dim3(512),
                               args, 0, stream);
}

// Round 5
// 5697.547 us; speedup vs baseline: 4.2465x; 4.2465x over previous
//
#include <hip/hip_runtime.h>
#include <hip/hip_bf16.h>
#include <stdint.h>

typedef __attribute__((ext_vector_type(8))) short short8;
typedef __attribute__((ext_vector_type(4))) float floatx4;

#define B_ 64
#define T_ 256
#define H_ 1024
#define LATENT_ 256
#define P_ 128
#define BH_ (B_ * H_)
#define MFMA_(a, b, c) __builtin_amdgcn_mfma_f32_16x16x32_bf16(a, b, c, 0, 0, 0)
// LDS column swizzle: breaks the 16-way bank conflict on cell-phase reads
// (write side stays <=2-way). pbuf is exactly 64 KB so no room for +1 pad.
#define PBI(n, row) (((n) + 4 * (row)) & 31)

__device__ __forceinline__ float sigmoidf_(float x) {
    return 1.0f / (1.0f + __expf(-x));
}
__device__ __forceinline__ float tanh_fast(float x) {
    float e = __expf(2.0f * x);
    return 1.0f - 2.0f / (e + 1.0f);
}

// Agent-scope (device) 16B A-fragment load as 2x8B atomic loads: emits
// global_load_dwordx2 with sc1 -> bypasses the reader's (possibly stale,
// non-coherent) XCD L2 and reads from L3 where sc1 stores landed.
__device__ __forceinline__ short8 ldA_sc(const short* p) {
    union { unsigned long long u[2]; short8 s; } v;
    const unsigned long long* q = (const unsigned long long*)p;
    v.u[0] = __hip_atomic_load(q,     __ATOMIC_RELAXED, __HIP_MEMORY_SCOPE_AGENT);
    v.u[1] = __hip_atomic_load(q + 1, __ATOMIC_RELAXED, __HIP_MEMORY_SCOPE_AGENT);
    return v.s;
}

// Wave GEMM segment: M=64 (4 m-tiles), N=32 (two B-frags), nchunks K-chunks
// of 32. A via agent-scope loads (mutable h state); weights via normal
// (L2-resident) loads. acc[2*mt+nt].
__device__ __forceinline__ void seg_sc(
    const short* A, long astr, const short* w0, const short* w1,
    int nchunks, floatx4* acc, int l15)
{
    for (int c = 0; c < nchunks; ++c) {
        short8 b0 = *(const short8*)(w0 + c * 32);
        short8 b1 = *(const short8*)(w1 + c * 32);
#pragma unroll
        for (int mt = 0; mt < 4; ++mt) {
            short8 a = ldA_sc(A + (long)(mt * 16 + l15) * astr + c * 32);
            acc[2 * mt]     = MFMA_(a, b0, acc[2 * mt]);
            acc[2 * mt + 1] = MFMA_(a, b1, acc[2 * mt + 1]);
        }
    }
}

// ---------------------------------------------------------------------------
__global__ __launch_bounds__(256) void cvt_f2b(
    const float* __restrict__ src, __hip_bfloat16* __restrict__ dst, int n)
{
    int i = (blockIdx.x * 256 + threadIdx.x) * 4;
    if (i < n) {
        float4 v = *(const float4*)(src + i);
        dst[i + 0] = __float2bfloat16(v.x);
        dst[i + 1] = __float2bfloat16(v.y);
        dst[i + 2] = __float2bfloat16(v.z);
        dst[i + 3] = __float2bfloat16(v.w);
    }
}

// h0 = z @ fc_init_w^T + fc_init_b -> both t=-1 ring slots; zero barrier cnts.
__global__ __launch_bounds__(256) void h0_kernel(
    const float* __restrict__ z,
    const float* __restrict__ fw,
    const float* __restrict__ fb,
    __hip_bfloat16* __restrict__ h1dst,
    __hip_bfloat16* __restrict__ h2dst,
    unsigned* __restrict__ cnt)
{
    if (blockIdx.x == 0 && threadIdx.x < 8) cnt[threadIdx.x * 64] = 0;
    int idx = blockIdx.x * 256 + threadIdx.x;   // 0..65535
    int b = idx >> 10, j = idx & 1023;
    const float* zp = z + b * LATENT_;
    const float* wp = fw + j * LATENT_;
    float acc = fb[j];
    for (int k = 0; k < LATENT_; k += 4) {
        float4 zv = *(const float4*)(zp + k);
        float4 wv = *(const float4*)(wp + k);
        acc += zv.x * wv.x + zv.y * wv.y + zv.z * wv.z + zv.w * wv.w;
    }
    __hip_bfloat16 hb = __float2bfloat16(acc);
    h1dst[idx] = hb;
    h2dst[idx] = hb;
}

struct PParams {
    const __hip_bfloat16 *tseqb, *stokb;
    const __hip_bfloat16 *Wih0b, *Whh0b, *Wih1b, *Whh1b, *owb;
    const float *bih0, *bhh0, *bih1, *bhh1, *ob;
    __hip_bfloat16 *h1ring;   // 2 * B*H
    __hip_bfloat16 *h2ring;   // 4 * B*H
    float* out;               // (B, T, P)
    unsigned* cnt;            // 8 counters, 256B apart
};

// ---------------------------------------------------------------------------
// Persistent pipelined LSTM. 256 blocks x 512 threads (8 waves), 1 block/CU.
//   blocks   0..127 : layer-1 step t=phase-1, 8 cols x 4 gates (N=32 rows)
//   blocks 128..255 : layer-0 step t=phase
//   blocks 128..135 : + out-projection of step phase-2
// Waves split K 8-way, each wave N=32 via dual B-frags (h read once/block).
// Custom barrier: monotonic agent-scope counters; NO cache-wide fences, so
// weights stay L2-resident (grid.sync's L2 inv was R4's 95us/phase).
// ---------------------------------------------------------------------------
__global__ __launch_bounds__(512, 2) void lstm_persistent(PParams p)
{
    __shared__ float pbuf[8][64][32];   // 64 KB partial-sum exchange
    const int tid  = threadIdx.x;
    const int bid  = blockIdx.x;
    const int wv   = tid >> 6;
    const int l    = tid & 63;
    const int l15  = l & 15;
    const int quad = l >> 4;
    const int ks   = quad * 8;
    const bool isL1 = bid < 128;
    const int colbase = (isL1 ? bid : bid - 128) * 8;
    // B-frag weight rows: nt=0 -> gates {i,f}, nt=1 -> gates {g,o}
    const int row0 = ((l15 >> 3)    ) * H_ + colbase + (l15 & 7);
    const int row1 = ((l15 >> 3) + 2) * H_ + colbase + (l15 & 7);

    // Cell duty: threads 0..255, two adjacent cells each (uint h-store).
    const int cm  = tid >> 2;          // batch row
    const int c0  = 2 * (tid & 3);     // first of the col pair
    const int cj0 = colbase + c0;
    const float* bi = isL1 ? p.bih1 : p.bih0;
    const float* bh = isL1 ? p.bhh1 : p.bhh0;
    float bs[8];                       // {i,f,g,o} x {c0, c0+1}
#pragma unroll
    for (int g = 0; g < 4; ++g) {
        bs[2 * g]     = bi[g * H_ + cj0]     + bh[g * H_ + cj0];
        bs[2 * g + 1] = bi[g * H_ + cj0 + 1] + bh[g * H_ + cj0 + 1];
    }
    float creg0 = 0.0f, creg1 = 0.0f;
    const bool outduty = (bid >= 128 && bid < 136);
    const int pbase = (bid - 128) * 16;

    for (int phase = 0; phase < T_ + 2; ++phase) {
        const bool doGemm = isL1 ? (phase >= 1 && phase <= T_) : (phase < T_);
        const int t = isL1 ? phase - 1 : phase;

        if (doGemm) {
            floatx4 acc[8] = {};
            if (isL1) {
                // gates1 = [h1(t) | h2(t-1)] @ [Wih1 | Whh1]^T, K=2048
                const short* Ab; const short* Wm; int kb;
                if (wv < 4) {
                    Ab = (const short*)p.h1ring + (long)(t & 1) * BH_;
                    Wm = (const short*)p.Wih1b;  kb = wv * 256;
                } else {
                    Ab = (const short*)p.h2ring + (long)((t - 1) & 3) * BH_;
                    Wm = (const short*)p.Whh1b;  kb = (wv - 4) * 256;
                }
                seg_sc(Ab + kb + ks, H_,
                       Wm + (long)row0 * H_ + kb + ks,
                       Wm + (long)row1 * H_ + kb + ks, 8, acc, l15);
            } else {
                // gates0 = [x_t | h1(t-1)] @ [Wih0 | Whh0]^T, K=128+1024
                const short* Ah = (const short*)p.h1ring
                                + (long)((t - 1) & 1) * BH_ + wv * 128 + ks;
                seg_sc(Ah, H_,
                       (const short*)p.Whh0b + (long)row0 * H_ + wv * 128 + ks,
                       (const short*)p.Whh0b + (long)row1 * H_ + wv * 128 + ks,
                       4, acc, l15);
                if (wv < 4) {   // x-part chunk wv (immutable -> normal loads)
                    const short* Ax; long xstr;
                    if (t == 0) { Ax = (const short*)p.stokb; xstr = 0; }
                    else { Ax = (const short*)p.tseqb + (long)(t - 1) * P_; xstr = (long)T_ * P_; }
                    short8 b0 = *(const short8*)((const short*)p.Wih0b + (long)row0 * P_ + wv * 32 + ks);
                    short8 b1 = *(const short8*)((const short*)p.Wih0b + (long)row1 * P_ + wv * 32 + ks);
#pragma unroll
                    for (int mt = 0; mt < 4; ++mt) {
                        short8 a = *(const short8*)(Ax + (long)(mt * 16 + l15) * xstr + wv * 32 + ks);
                        acc[2 * mt]     = MFMA_(a, b0, acc[2 * mt]);
                        acc[2 * mt + 1] = MFMA_(a, b1, acc[2 * mt + 1]);
                    }
                }
            }
            // C/D: col = lane&15, row = quad*4 + reg (+ mt*16)
#pragma unroll
            for (int mt = 0; mt < 4; ++mt)
#pragma unroll
                for (int nt = 0; nt < 2; ++nt)
#pragma unroll
                    for (int r = 0; r < 4; ++r) {
                        int row = mt * 16 + quad * 4 + r;
                        pbuf[wv][row][PBI(nt * 16 + l15, row)] = acc[2 * mt + nt][r];
                    }
        }
        __syncthreads();
        if (doGemm && tid < 256) {
            // gate n-layout: i: [0,8) f: [8,16) g: [16,24) o: [24,32)
            float v[8];
#pragma unroll
            for (int k = 0; k < 8; ++k) v[k] = bs[k];
#pragma unroll
            for (int w2 = 0; w2 < 8; ++w2)
#pragma unroll
                for (int g = 0; g < 4; ++g) {
                    v[2 * g]     += pbuf[w2][cm][PBI(8 * g + c0,     cm)];
                    v[2 * g + 1] += pbuf[w2][cm][PBI(8 * g + c0 + 1, cm)];
                }
            float cn0 = sigmoidf_(v[2]) * creg0 + sigmoidf_(v[0]) * tanh_fast(v[4]);
            float cn1 = sigmoidf_(v[3]) * creg1 + sigmoidf_(v[1]) * tanh_fast(v[5]);
            float hv0 = sigmoidf_(v[6]) * tanh_fast(cn0);
            float hv1 = sigmoidf_(v[7]) * tanh_fast(cn1);
            creg0 = cn0; creg1 = cn1;
            __hip_bfloat16* hdst = isL1 ? (p.h2ring + (long)(t & 3) * BH_)
                                        : (p.h1ring + (long)(t & 1) * BH_);
            __hip_bfloat16 hb0 = __float2bfloat16(hv0), hb1 = __float2bfloat16(hv1);
            unsigned pk = ((unsigned)*(unsigned short*)&hb1 << 16) | *(unsigned short*)&hb0;
            // sc1 write-through -> visible at L3 once vmcnt-drained.
            __hip_atomic_store((unsigned*)(hdst + cm * H_ + cj0), pk,
                               __ATOMIC_RELAXED, __HIP_MEMORY_SCOPE_AGENT);
        }

        if (outduty && phase >= 2) {
            int t2 = phase - 2;
            __syncthreads();   // cell reads of pbuf done; safe to overwrite
            floatx4 oacc[4] = {};
            const short* Ab = (const short*)p.h2ring + (long)(t2 & 3) * BH_ + wv * 128 + ks;
            const short* Wb = (const short*)p.owb + (long)(pbase + l15) * H_ + wv * 128 + ks;
            for (int c2 = 0; c2 < 4; ++c2) {
                short8 b0 = *(const short8*)(Wb + c2 * 32);
#pragma unroll
                for (int mt = 0; mt < 4; ++mt) {
                    short8 a = ldA_sc(Ab + (long)(mt * 16 + l15) * H_ + c2 * 32);
                    oacc[mt] = MFMA_(a, b0, oacc[mt]);
                }
            }
#pragma unroll
            for (int mt = 0; mt < 4; ++mt)
#pragma unroll
                for (int r = 0; r < 4; ++r)
                    pbuf[wv][mt * 16 + quad * 4 + r][l15] = oacc[mt][r];
            __syncthreads();
#pragma unroll
            for (int q2 = 0; q2 < 2; ++q2) {
                int e = tid + q2 * 512, m = e >> 4, pp = e & 15;
                float v = p.ob[pbase + pp];
#pragma unroll
                for (int w2 = 0; w2 < 8; ++w2) v += pbuf[w2][m][pp];
                p.out[(long)m * (T_ * P_) + (long)t2 * P_ + pbase + pp] = sigmoidf_(v);
            }
        }

        // __syncthreads drains each wave's vmcnt(0) (h stores complete at L3)
        __syncthreads();
        if (tid == 0) {
            __hip_atomic_fetch_add(p.cnt + (bid & 7) * 64, 1u,
                                   __ATOMIC_RELAXED, __HIP_MEMORY_SCOPE_AGENT);
            unsigned target = 256u * (unsigned)(phase + 1);
            for (;;) {
                unsigned s = 0;
#pragma unroll
                for (int i2 = 0; i2 < 8; ++i2)
                    s += __hip_atomic_load(p.cnt + i2 * 64,
                                           __ATOMIC_RELAXED, __HIP_MEMORY_SCOPE_AGENT);
                if (s >= target) break;
                __builtin_amdgcn_s_sleep(1);
            }
        }
        asm volatile("" ::: "memory");   // compiler fence: no hoisting past spin
        __syncthreads();
    }
}

// ---------------------------------------------------------------------------
extern "C" void kernel_launch(void* const* d_in, const int* in_sizes, int n_in,
                              void* d_out, int out_size, void* d_ws, size_t ws_size,
                              hipStream_t stream) {
    const float* z    = (const float*)d_in[0];
    const float* tseq = (const float*)d_in[1];
    const float* fw   = (const float*)d_in[2];
    const float* fb   = (const float*)d_in[3];
    const float* stok = (const float*)d_in[4];
    const float* Wih0 = (const float*)d_in[5];
    const float* Whh0 = (const float*)d_in[6];
    const float* bih0 = (const float*)d_in[7];
    const float* bhh0 = (const float*)d_in[8];
    const float* Wih1 = (const float*)d_in[9];
    const float* Whh1 = (const float*)d_in[10];
    const float* bih1 = (const float*)d_in[11];
    const float* bhh1 = (const float*)d_in[12];
    const float* ow   = (const float*)d_in[13];
    const float* ob   = (const float*)d_in[14];
    float* out = (float*)d_out;

    // Workspace (~30.2 MB)
    char* ws = (char*)d_ws;
    size_t off = 0;
    __hip_bfloat16* Wih0b = (__hip_bfloat16*)(ws + off); off += (size_t)4 * H_ * P_ * 2;
    __hip_bfloat16* Whh0b = (__hip_bfloat16*)(ws + off); off += (size_t)4 * H_ * H_ * 2;
    __hip_bfloat16* Wih1b = (__hip_bfloat16*)(ws + off); off += (size_t)4 * H_ * H_ * 2;
    __hip_bfloat16* Whh1b = (__hip_bfloat16*)(ws + off); off += (size_t)4 * H_ * H_ * 2;
    __hip_bfloat16* owb   = (__hip_bfloat16*)(ws + off); off += (size_t)P_ * H_ * 2;
    __hip_bfloat16* tseqb = (__hip_bfloat16*)(ws + off); off += (size_t)B_ * T_ * P_ * 2;
    __hip_bfloat16* stokb = (__hip_bfloat16*)(ws + off); off += 256;
    __hip_bfloat16* h1ring= (__hip_bfloat16*)(ws + off); off += (size_t)2 * BH_ * 2;
    __hip_bfloat16* h2ring= (__hip_bfloat16*)(ws + off); off += (size_t)4 * BH_ * 2;
    unsigned* cnt         = (unsigned*)(ws + off);       off += 8 * 256;

    auto cvt = [&](const float* s, __hip_bfloat16* d, int n) {
        hipLaunchKernelGGL(cvt_f2b, dim3((n / 4 + 255) / 256), dim3(256), 0, stream, s, d, n);
    };
    cvt(Wih0, Wih0b, 4 * H_ * P_);
    cvt(Whh0, Whh0b, 4 * H_ * H_);
    cvt(Wih1, Wih1b, 4 * H_ * H_);
    cvt(Whh1, Whh1b, 4 * H_ * H_);
    cvt(ow,   owb,   P_ * H_);
    cvt(tseq, tseqb, B_ * T_ * P_);
    cvt(stok, stokb, P_);

    // h0 into t=-1 slots: h1 slot (-1)&1 = 1, h2 slot (-1)&3 = 3.
    hipLaunchKernelGGL(h0_kernel, dim3(256), dim3(256), 0, stream,
                       z, fw, fb, h1ring + (size_t)1 * BH_, h2ring + (size_t)3 * BH_, cnt);

    PParams pp;
    pp.tseqb = tseqb; pp.stokb = stokb;
    pp.Wih0b = Wih0b; pp.Whh0b = Whh0b; pp.Wih1b = Wih1b; pp.Whh1b = Whh1b;
    pp.owb = owb;
    pp.bih0 = bih0; pp.bhh0 = bhh0; pp.bih1 = bih1; pp.bhh1 = bhh1; pp.ob = ob;
    pp.h1ring = h1ring; pp.h2ring = h2ring;
    pp.out = out;
    pp.cnt = cnt;
    void* args[] = { &pp };
    hipLaunchCooperativeKernel((void*)lstm_persistent, dim3(256), dim3(512),
                               args, 0, stream);
}

// Round 6
// 5447.197 us; speedup vs baseline: 4.4417x; 1.0460x over previous
//
#include <hip/hip_runtime.h>
#include <hip/hip_bf16.h>
#include <stdint.h>

typedef __attribute__((ext_vector_type(8))) short short8;
typedef __attribute__((ext_vector_type(4))) float floatx4;

#define B_ 64
#define T_ 256
#define H_ 1024
#define LATENT_ 256
#define P_ 128
#define BH_ (B_ * H_)
#define MFMA_(a, b, c) __builtin_amdgcn_mfma_f32_16x16x32_bf16(a, b, c, 0, 0, 0)
// LDS column swizzle: breaks the 16-way bank conflict on cell-phase reads
// (write side stays <=2-way). pbuf is exactly 64 KB so no room for +1 pad.
#define PBI(n, row) (((n) + 4 * (row)) & 31)

__device__ __forceinline__ float sigmoidf_(float x) {
    return 1.0f / (1.0f + __expf(-x));
}
__device__ __forceinline__ float tanh_fast(float x) {
    float e = __expf(2.0f * x);
    return 1.0f - 2.0f / (e + 1.0f);
}

// Agent-scope (device) 16B A-fragment load as 2x8B atomic loads: emits
// global_load_dwordx2 with sc1 -> bypasses the reader's (possibly stale,
// non-coherent) XCD L2 and reads from L3 where sc1 stores landed.
__device__ __forceinline__ short8 ldA_sc(const short* p) {
    union { unsigned long long u[2]; short8 s; } v;
    const unsigned long long* q = (const unsigned long long*)p;
    v.u[0] = __hip_atomic_load(q,     __ATOMIC_RELAXED, __HIP_MEMORY_SCOPE_AGENT);
    v.u[1] = __hip_atomic_load(q + 1, __ATOMIC_RELAXED, __HIP_MEMORY_SCOPE_AGENT);
    return v.s;
}

// Wave GEMM segment: M=64 (4 m-tiles), N=32 (two B-frags), nchunks K-chunks
// of 32. A via agent-scope loads (mutable h state); weights via normal
// (L2-resident) loads. acc[2*mt+nt].
__device__ __forceinline__ void seg_sc(
    const short* A, long astr, const short* w0, const short* w1,
    int nchunks, floatx4* acc, int l15)
{
    for (int c = 0; c < nchunks; ++c) {
        short8 b0 = *(const short8*)(w0 + c * 32);
        short8 b1 = *(const short8*)(w1 + c * 32);
#pragma unroll
        for (int mt = 0; mt < 4; ++mt) {
            short8 a = ldA_sc(A + (long)(mt * 16 + l15) * astr + c * 32);
            acc[2 * mt]     = MFMA_(a, b0, acc[2 * mt]);
            acc[2 * mt + 1] = MFMA_(a, b1, acc[2 * mt + 1]);
        }
    }
}

// ---------------------------------------------------------------------------
__global__ __launch_bounds__(256) void cvt_f2b(
    const float* __restrict__ src, __hip_bfloat16* __restrict__ dst, int n)
{
    int i = (blockIdx.x * 256 + threadIdx.x) * 4;
    if (i < n) {
        float4 v = *(const float4*)(src + i);
        dst[i + 0] = __float2bfloat16(v.x);
        dst[i + 1] = __float2bfloat16(v.y);
        dst[i + 2] = __float2bfloat16(v.z);
        dst[i + 3] = __float2bfloat16(v.w);
    }
}

// h0 = z @ fc_init_w^T + fc_init_b -> both t=-1 ring slots; zero barrier
// counters (8 lines) + release flag (9th line).
__global__ __launch_bounds__(256) void h0_kernel(
    const float* __restrict__ z,
    const float* __restrict__ fw,
    const float* __restrict__ fb,
    __hip_bfloat16* __restrict__ h1dst,
    __hip_bfloat16* __restrict__ h2dst,
    unsigned* __restrict__ cnt)
{
    if (blockIdx.x == 0 && threadIdx.x < 9) cnt[threadIdx.x * 64] = 0;
    int idx = blockIdx.x * 256 + threadIdx.x;   // 0..65535
    int b = idx >> 10, j = idx & 1023;
    const float* zp = z + b * LATENT_;
    const float* wp = fw + j * LATENT_;
    float acc = fb[j];
    for (int k = 0; k < LATENT_; k += 4) {
        float4 zv = *(const float4*)(zp + k);
        float4 wv = *(const float4*)(wp + k);
        acc += zv.x * wv.x + zv.y * wv.y + zv.z * wv.z + zv.w * wv.w;
    }
    __hip_bfloat16 hb = __float2bfloat16(acc);
    h1dst[idx] = hb;
    h2dst[idx] = hb;
}

struct PParams {
    const __hip_bfloat16 *tseqb, *stokb;
    const __hip_bfloat16 *Wih0b, *Whh0b, *Wih1b, *Whh1b, *owb;
    const float *bih0, *bhh0, *bih1, *bhh1, *ob;
    __hip_bfloat16 *h1ring;   // 2 * B*H
    __hip_bfloat16 *h2ring;   // 4 * B*H
    float* out;               // (B, T, P)
    unsigned* cnt;            // 8 arrive counters (256B apart) + flag line
};

// ---------------------------------------------------------------------------
// Persistent pipelined LSTM. 256 blocks x 512 threads (8 waves), 1 block/CU.
//   blocks   0..127 : layer-1 step t=phase-1, 8 cols x 4 gates (N=32 rows)
//   blocks 128..255 : layer-0 step t=phase
//   blocks 128..135 : + out-projection of step phase-2
// Waves split K 8-way, each wave N=32 via dual B-frags (h read once/block).
// Barrier: striped arrive counters + leader-aggregated single release flag
// (R5's all-spin-on-8-lines was a read storm that serialized the arrives:
//  21.5us/phase with 3% busy).
// ---------------------------------------------------------------------------
__global__ __launch_bounds__(512, 2) void lstm_persistent(PParams p)
{
    __shared__ float pbuf[8][64][32];   // 64 KB partial-sum exchange
    const int tid  = threadIdx.x;
    const int bid  = blockIdx.x;
    const int wv   = tid >> 6;
    const int l    = tid & 63;
    const int l15  = l & 15;
    const int quad = l >> 4;
    const int ks   = quad * 8;
    const bool isL1 = bid < 128;
    const int colbase = (isL1 ? bid : bid - 128) * 8;
    // B-frag weight rows: nt=0 -> gates {i,f}, nt=1 -> gates {g,o}
    const int row0 = ((l15 >> 3)    ) * H_ + colbase + (l15 & 7);
    const int row1 = ((l15 >> 3) + 2) * H_ + colbase + (l15 & 7);

    // Cell duty: threads 0..255, two adjacent cells each (uint h-store).
    const int cm  = tid >> 2;          // batch row
    const int c0  = 2 * (tid & 3);     // first of the col pair
    const int cj0 = colbase + c0;
    const float* bi = isL1 ? p.bih1 : p.bih0;
    const float* bh = isL1 ? p.bhh1 : p.bhh0;
    float bs[8];                       // {i,f,g,o} x {c0, c0+1}
#pragma unroll
    for (int g = 0; g < 4; ++g) {
        bs[2 * g]     = bi[g * H_ + cj0]     + bh[g * H_ + cj0];
        bs[2 * g + 1] = bi[g * H_ + cj0 + 1] + bh[g * H_ + cj0 + 1];
    }
    float creg0 = 0.0f, creg1 = 0.0f;
    const bool outduty = (bid >= 128 && bid < 136);
    const int pbase = (bid - 128) * 16;
    unsigned* const flag = p.cnt + 8 * 64;   // release generation line

    for (int phase = 0; phase < T_ + 2; ++phase) {
        const bool doGemm = isL1 ? (phase >= 1 && phase <= T_) : (phase < T_);
        const int t = isL1 ? phase - 1 : phase;

        if (doGemm) {
            floatx4 acc[8] = {};
            if (isL1) {
                // gates1 = [h1(t) | h2(t-1)] @ [Wih1 | Whh1]^T, K=2048
                const short* Ab; const short* Wm; int kb;
                if (wv < 4) {
                    Ab = (const short*)p.h1ring + (long)(t & 1) * BH_;
                    Wm = (const short*)p.Wih1b;  kb = wv * 256;
                } else {
                    Ab = (const short*)p.h2ring + (long)((t - 1) & 3) * BH_;
                    Wm = (const short*)p.Whh1b;  kb = (wv - 4) * 256;
                }
                seg_sc(Ab + kb + ks, H_,
                       Wm + (long)row0 * H_ + kb + ks,
                       Wm + (long)row1 * H_ + kb + ks, 8, acc, l15);
            } else {
                // gates0 = [x_t | h1(t-1)] @ [Wih0 | Whh0]^T, K=128+1024
                const short* Ah = (const short*)p.h1ring
                                + (long)((t - 1) & 1) * BH_ + wv * 128 + ks;
                seg_sc(Ah, H_,
                       (const short*)p.Whh0b + (long)row0 * H_ + wv * 128 + ks,
                       (const short*)p.Whh0b + (long)row1 * H_ + wv * 128 + ks,
                       4, acc, l15);
                if (wv < 4) {   // x-part chunk wv (immutable -> normal loads)
                    const short* Ax; long xstr;
                    if (t == 0) { Ax = (const short*)p.stokb; xstr = 0; }
                    else { Ax = (const short*)p.tseqb + (long)(t - 1) * P_; xstr = (long)T_ * P_; }
                    short8 b0 = *(const short8*)((const short*)p.Wih0b + (long)row0 * P_ + wv * 32 + ks);
                    short8 b1 = *(const short8*)((const short*)p.Wih0b + (long)row1 * P_ + wv * 32 + ks);
#pragma unroll
                    for (int mt = 0; mt < 4; ++mt) {
                        short8 a = *(const short8*)(Ax + (long)(mt * 16 + l15) * xstr + wv * 32 + ks);
                        acc[2 * mt]     = MFMA_(a, b0, acc[2 * mt]);
                        acc[2 * mt + 1] = MFMA_(a, b1, acc[2 * mt + 1]);
                    }
                }
            }
            // C/D: col = lane&15, row = quad*4 + reg (+ mt*16)
#pragma unroll
            for (int mt = 0; mt < 4; ++mt)
#pragma unroll
                for (int nt = 0; nt < 2; ++nt)
#pragma unroll
                    for (int r = 0; r < 4; ++r) {
                        int row = mt * 16 + quad * 4 + r;
                        pbuf[wv][row][PBI(nt * 16 + l15, row)] = acc[2 * mt + nt][r];
                    }
        }
        __syncthreads();
        if (doGemm && tid < 256) {
            // gate n-layout: i: [0,8) f: [8,16) g: [16,24) o: [24,32)
            float v[8];
#pragma unroll
            for (int k = 0; k < 8; ++k) v[k] = bs[k];
#pragma unroll
            for (int w2 = 0; w2 < 8; ++w2)
#pragma unroll
                for (int g = 0; g < 4; ++g) {
                    v[2 * g]     += pbuf[w2][cm][PBI(8 * g + c0,     cm)];
                    v[2 * g + 1] += pbuf[w2][cm][PBI(8 * g + c0 + 1, cm)];
                }
            float cn0 = sigmoidf_(v[2]) * creg0 + sigmoidf_(v[0]) * tanh_fast(v[4]);
            float cn1 = sigmoidf_(v[3]) * creg1 + sigmoidf_(v[1]) * tanh_fast(v[5]);
            float hv0 = sigmoidf_(v[6]) * tanh_fast(cn0);
            float hv1 = sigmoidf_(v[7]) * tanh_fast(cn1);
            creg0 = cn0; creg1 = cn1;
            __hip_bfloat16* hdst = isL1 ? (p.h2ring + (long)(t & 3) * BH_)
                                        : (p.h1ring + (long)(t & 1) * BH_);
            __hip_bfloat16 hb0 = __float2bfloat16(hv0), hb1 = __float2bfloat16(hv1);
            unsigned pk = ((unsigned)*(unsigned short*)&hb1 << 16) | *(unsigned short*)&hb0;
            // sc1 write-through -> visible at L3 once vmcnt-drained.
            __hip_atomic_store((unsigned*)(hdst + cm * H_ + cj0), pk,
                               __ATOMIC_RELAXED, __HIP_MEMORY_SCOPE_AGENT);
        }

        if (outduty && phase >= 2) {
            int t2 = phase - 2;
            __syncthreads();   // cell reads of pbuf done; safe to overwrite
            floatx4 oacc[4] = {};
            const short* Ab = (const short*)p.h2ring + (long)(t2 & 3) * BH_ + wv * 128 + ks;
            const short* Wb = (const short*)p.owb + (long)(pbase + l15) * H_ + wv * 128 + ks;
            for (int c2 = 0; c2 < 4; ++c2) {
                short8 b0 = *(const short8*)(Wb + c2 * 32);
#pragma unroll
                for (int mt = 0; mt < 4; ++mt) {
                    short8 a = ldA_sc(Ab + (long)(mt * 16 + l15) * H_ + c2 * 32);
                    oacc[mt] = MFMA_(a, b0, oacc[mt]);
                }
            }
#pragma unroll
            for (int mt = 0; mt < 4; ++mt)
#pragma unroll
                for (int r = 0; r < 4; ++r)
                    pbuf[wv][mt * 16 + quad * 4 + r][l15] = oacc[mt][r];
            __syncthreads();
#pragma unroll
            for (int q2 = 0; q2 < 2; ++q2) {
                int e = tid + q2 * 512, m = e >> 4, pp = e & 15;
                float v = p.ob[pbase + pp];
#pragma unroll
                for (int w2 = 0; w2 < 8; ++w2) v += pbuf[w2][m][pp];
                p.out[(long)m * (T_ * P_) + (long)t2 * P_ + pbase + pp] = sigmoidf_(v);
            }
        }

        // __syncthreads drains each wave's vmcnt(0) (h stores complete at L3)
        __syncthreads();
        if (tid == 0) {
            __hip_atomic_fetch_add(p.cnt + (bid & 7) * 64, 1u,
                                   __ATOMIC_RELAXED, __HIP_MEMORY_SCOPE_AGENT);
            unsigned gen = (unsigned)(phase + 1);
            if (bid == 0) {
                // Leader: aggregate the 8 arrive counters, then publish gen.
                unsigned target = 256u * gen;
                for (;;) {
                    unsigned s = 0;
#pragma unroll
                    for (int i2 = 0; i2 < 8; ++i2)
                        s += __hip_atomic_load(p.cnt + i2 * 64,
                                               __ATOMIC_RELAXED, __HIP_MEMORY_SCOPE_AGENT);
                    if (s >= target) break;
                    __builtin_amdgcn_s_sleep(1);
                }
                asm volatile("" ::: "memory");
                __hip_atomic_store(flag, gen,
                                   __ATOMIC_RELAXED, __HIP_MEMORY_SCOPE_AGENT);
            } else {
                // Everyone else polls ONE line with backoff (no read storm).
                while (__hip_atomic_load(flag, __ATOMIC_RELAXED,
                                         __HIP_MEMORY_SCOPE_AGENT) < gen)
                    __builtin_amdgcn_s_sleep(8);
            }
        }
        asm volatile("" ::: "memory");   // compiler fence: no hoisting past spin
        __syncthreads();
    }
}

// ---------------------------------------------------------------------------
extern "C" void kernel_launch(void* const* d_in, const int* in_sizes, int n_in,
                              void* d_out, int out_size, void* d_ws, size_t ws_size,
                              hipStream_t stream) {
    const float* z    = (const float*)d_in[0];
    const float* tseq = (const float*)d_in[1];
    const float* fw   = (const float*)d_in[2];
    const float* fb   = (const float*)d_in[3];
    const float* stok = (const float*)d_in[4];
    const float* Wih0 = (const float*)d_in[5];
    const float* Whh0 = (const float*)d_in[6];
    const float* bih0 = (const float*)d_in[7];
    const float* bhh0 = (const float*)d_in[8];
    const float* Wih1 = (const float*)d_in[9];
    const float* Whh1 = (const float*)d_in[10];
    const float* bih1 = (const float*)d_in[11];
    const float* bhh1 = (const float*)d_in[12];
    const float* ow   = (const float*)d_in[13];
    const float* ob   = (const float*)d_in[14];
    float* out = (float*)d_out;

    // Workspace (~30.2 MB)
    char* ws = (char*)d_ws;
    size_t off = 0;
    __hip_bfloat16* Wih0b = (__hip_bfloat16*)(ws + off); off += (size_t)4 * H_ * P_ * 2;
    __hip_bfloat16* Whh0b = (__hip_bfloat16*)(ws + off); off += (size_t)4 * H_ * H_ * 2;
    __hip_bfloat16* Wih1b = (__hip_bfloat16*)(ws + off); off += (size_t)4 * H_ * H_ * 2;
    __hip_bfloat16* Whh1b = (__hip_bfloat16*)(ws + off); off += (size_t)4 * H_ * H_ * 2;
    __hip_bfloat16* owb   = (__hip_bfloat16*)(ws + off); off += (size_t)P_ * H_ * 2;
    __hip_bfloat16* tseqb = (__hip_bfloat16*)(ws + off); off += (size_t)B_ * T_ * P_ * 2;
    __hip_bfloat16* stokb = (__hip_bfloat16*)(ws + off); off += 256;
    __hip_bfloat16* h1ring= (__hip_bfloat16*)(ws + off); off += (size_t)2 * BH_ * 2;
    __hip_bfloat16* h2ring= (__hip_bfloat16*)(ws + off); off += (size_t)4 * BH_ * 2;
    unsigned* cnt         = (unsigned*)(ws + off);       off += 9 * 256;

    auto cvt = [&](const float* s, __hip_bfloat16* d, int n) {
        hipLaunchKernelGGL(cvt_f2b, dim3((n / 4 + 255) / 256), dim3(256), 0, stream, s, d, n);
    };
    cvt(Wih0, Wih0b, 4 * H_ * P_);
    cvt(Whh0, Whh0b, 4 * H_ * H_);
    cvt(Wih1, Wih1b, 4 * H_ * H_);
    cvt(Whh1, Whh1b, 4 * H_ * H_);
    cvt(ow,   owb,   P_ * H_);
    cvt(tseq, tseqb, B_ * T_ * P_);
    cvt(stok, stokb, P_);

    // h0 into t=-1 slots: h1 slot (-1)&1 = 1, h2 slot (-1)&3 = 3.
    hipLaunchKernelGGL(h0_kernel, dim3(256), dim3(256), 0, stream,
                       z, fw, fb, h1ring + (size_t)1 * BH_, h2ring + (size_t)3 * BH_, cnt);

    PParams pp;
    pp.tseqb = tseqb; pp.stokb = stokb;
    pp.Wih0b = Wih0b; pp.Whh0b = Whh0b; pp.Wih1b = Wih1b; pp.Whh1b = Whh1b;
    pp.owb = owb;
    pp.bih0 = bih0; pp.bhh0 = bhh0; pp.bih1 = bih1; pp.bhh1 = bhh1; pp.ob = ob;
    pp.h1ring = h1ring; pp.h2ring = h2ring;
    pp.out = out;
    pp.cnt = cnt;
    void* args[] = { &pp };
    hipLaunchCooperativeKernel((void*)lstm_persistent, dim3(256), dim3(512),
                               args, 0, stream);
}